// Round 1
// baseline (282.103 us; speedup 1.0000x reference)
//
#include <hip/hip_runtime.h>

// MaskedEmbedding: out[t, :] = (mask_real[x[t], :] > THR ? weight[x[t], :] : 0)
// x: [B*S] int32, mask_real/weight: [VOCAB, D] fp32, out: [B*S, D] fp32.
// Pure HBM-streaming gather: one block per token, one float4 per lane.

#define D_DIM 768
#define D4 (D_DIM / 4)   // 192 float4 per row
#define THR 0.01f

__global__ __launch_bounds__(D4) void masked_embedding_kernel(
    const int* __restrict__ x,
    const float4* __restrict__ mask,
    const float4* __restrict__ weight,
    float4* __restrict__ out)
{
    const int token = blockIdx.x;     // 0 .. B*S-1
    const int col   = threadIdx.x;    // 0 .. 191 (float4 columns)

    // Block-uniform row index -> scalar load path.
    const int row = x[token];

    const size_t src = (size_t)row * D4 + col;
    const float4 m = mask[src];
    const float4 w = weight[src];

    float4 o;
    o.x = (m.x > THR) ? w.x : 0.0f;
    o.y = (m.y > THR) ? w.y : 0.0f;
    o.z = (m.z > THR) ? w.z : 0.0f;
    o.w = (m.w > THR) ? w.w : 0.0f;

    out[(size_t)token * D4 + col] = o;
}

extern "C" void kernel_launch(void* const* d_in, const int* in_sizes, int n_in,
                              void* d_out, int out_size, void* d_ws, size_t ws_size,
                              hipStream_t stream)
{
    const int*    x      = (const int*)d_in[0];     // [B*S]
    const float4* mask   = (const float4*)d_in[1];  // [VOCAB, D]
    const float4* weight = (const float4*)d_in[2];  // [VOCAB, D]
    float4*       out    = (float4*)d_out;          // [B*S, D]

    const int n_tokens = in_sizes[0];               // B*S = 16384

    masked_embedding_kernel<<<n_tokens, D4, 0, stream>>>(x, mask, weight, out);
}